// Round 1
// 486.879 us; speedup vs baseline: 1.2169x; 1.2169x over previous
//
#include <hip/hip_runtime.h>
#include <hip/hip_bf16.h>
#include <stdint.h>

typedef __bf16 bf16x8 __attribute__((ext_vector_type(8)));
typedef float f32x4 __attribute__((ext_vector_type(4)));
typedef unsigned int u32;
typedef __attribute__((address_space(1))) const u32 g_u32;
typedef __attribute__((address_space(3))) u32 l_u32;

__device__ __forceinline__ unsigned short f32_bf16_rne(float f) {
    unsigned u = __float_as_uint(f);
    u += 0x7FFFu + ((u >> 16) & 1u);
    return (unsigned short)(u >> 16);
}

__device__ __forceinline__ float fast_tanh(float z) {
    // 1 - 2/(1+e^{2z}); exact limits at +-inf, error << bf16 quantization
    return 1.0f - 2.0f / (1.0f + __expf(2.0f * z));
}

__device__ __forceinline__ void lds16(const void* g, void* l) {
    __builtin_amdgcn_global_load_lds((g_u32*)g, (l_u32*)l, 16, 0, 0);
}

// ---- fused prep: blocks [0,qblocks) transpose+quantize W; rest convert x ----
__global__ __launch_bounds__(256) void prep(
    const float* __restrict__ x, unsigned short* __restrict__ xb, int n8,
    const float* __restrict__ W, unsigned short* __restrict__ Wt,
    const float* __restrict__ kk_p, int K, int N, int qbx, int qblocks)
{
    const int t = threadIdx.x;
    if ((int)blockIdx.x < qblocks) {
        // ---- W[k][n] -> quant -> Wt[n][k], 64x64 tile ----
        __shared__ unsigned short tileT[64][66];   // [n_local][k_local], 33-word stride
        const float kk = *kk_p;
        const bool soft = kk < 1000.0f;
        const int nb = (blockIdx.x % qbx) * 64;
        const int kb = (blockIdx.x / qbx) * 64;
#pragma unroll
        for (int j = 0; j < 4; ++j) {
            const int r  = j * 16 + (t >> 4);     // k_local
            const int c4 = (t & 15) * 4;          // n_local base
            float4 w = *(const float4*)&W[(size_t)(kb + r) * N + nb + c4];
            float q0, q1, q2, q3;
            if (soft) {
                q0 = fast_tanh(w.x * kk); q1 = fast_tanh(w.y * kk);
                q2 = fast_tanh(w.z * kk); q3 = fast_tanh(w.w * kk);
            } else {
                q0 = (w.x > 0.f) ? 1.f : (w.x < 0.f ? -1.f : 0.f);
                q1 = (w.y > 0.f) ? 1.f : (w.y < 0.f ? -1.f : 0.f);
                q2 = (w.z > 0.f) ? 1.f : (w.z < 0.f ? -1.f : 0.f);
                q3 = (w.w > 0.f) ? 1.f : (w.w < 0.f ? -1.f : 0.f);
            }
            tileT[c4 + 0][r] = f32_bf16_rne(q0);
            tileT[c4 + 1][r] = f32_bf16_rne(q1);
            tileT[c4 + 2][r] = f32_bf16_rne(q2);
            tileT[c4 + 3][r] = f32_bf16_rne(q3);
        }
        __syncthreads();
#pragma unroll
        for (int j = 0; j < 2; ++j) {
            const int n = j * 32 + (t >> 3);
            const int c = (t & 7) * 8;            // covers k_local 0..63
            uint4 v;
            v.x = *(const u32*)&tileT[n][c + 0];
            v.y = *(const u32*)&tileT[n][c + 2];
            v.z = *(const u32*)&tileT[n][c + 4];
            v.w = *(const u32*)&tileT[n][c + 6];
            *(uint4*)&Wt[(size_t)(nb + n) * K + kb + c] = v;
        }
    } else {
        // ---- x fp32 -> bf16, 8 elems/thread ----
        const int i = ((int)blockIdx.x - qblocks) * 256 + t;
        if (i >= n8) return;
        const float4* p = (const float4*)x + (size_t)i * 2;
        float4 a = p[0];
        float4 b = p[1];
        union { unsigned short u[8]; uint4 v; } o;
        o.u[0] = f32_bf16_rne(a.x); o.u[1] = f32_bf16_rne(a.y);
        o.u[2] = f32_bf16_rne(a.z); o.u[3] = f32_bf16_rne(a.w);
        o.u[4] = f32_bf16_rne(b.x); o.u[5] = f32_bf16_rne(b.y);
        o.u[6] = f32_bf16_rne(b.z); o.u[7] = f32_bf16_rne(b.w);
        *((uint4*)xb + i) = o.v;
    }
}

// =====================  256x256 8-phase bf16 GEMM  =====================
// C = nmk * A(MxK) @ Bt(NxK)^T + bias, bf16 inputs, fp32 out.
// 8 waves (2M x 4N), BK=64, per-wave 128x64 out = 8x4 frags of 16x16x32.
// LDS 128 KiB: 2 buffers x (A 32K + B 32K). Staging = global_load_lds w16,
// linear dest; bank swizzle applied via pre-swizzled GLOBAL source +
// swizzled ds_read (both-sides rule). Subtile = 16 rows x 32 cols (1024 B),
// chunk-in-row c4 stored at c4 ^ ((r4>>1)&3)  -> 2-way banks (free).
// Schedule per K-tile t (4 phases):
//   p0: read B(t) x8 + A-q0 x4 ; stage A(t+1) h0
//   p1: read A-q1              ; stage A(t+1) h1
//   p2: read A-q2              ; stage B(t+2) h0
//   p3: read A-q3              ; stage B(t+2) h1 ; vmcnt(4)
// each phase: reads -> stage -> barrier -> lgkmcnt(0) -> setprio(1) ->
//             16 MFMA -> setprio(0) -> barrier.  vmcnt never 0 in loop.
__global__ __launch_bounds__(512, 2) void gemm_bf16_256(
    const unsigned short* __restrict__ A,   // [M][K] bf16
    const unsigned short* __restrict__ Bt,  // [N][K] bf16
    const float* __restrict__ bias,
    const float* __restrict__ nmk_p,
    float* __restrict__ C,
    int M, int N, int K)
{
    __shared__ __align__(16) char lds[131072];

    const int tid  = threadIdx.x;
    const int wave = tid >> 6;
    const int lane = tid & 63;
    const int wr = wave >> 2;        // 0..1
    const int wc = wave & 3;         // 0..3

    // bijective XCD swizzle (m204)
    const int nbx = N >> 8;
    const int nwg = (int)gridDim.x;
    int id = (int)blockIdx.x;
    {
        const int xcd = id & 7, lid = id >> 3;
        const int q8 = nwg >> 3, r8 = nwg & 7;
        id = (xcd < r8 ? xcd * (q8 + 1) : r8 * (q8 + 1) + (xcd - r8) * q8) + lid;
    }
    const int mTile = (id / nbx) << 8;
    const int nTile = (id % nbx) << 8;

    // ---- staging source decode (inverse swizzle on global source) ----
    const size_t Kb = (size_t)K * 2;          // global row bytes
    const char* pA[2];
    const char* pB[2];
#pragma unroll
    for (int q = 0; q < 2; ++q) {
        const int s  = (wave * 2 + q) * 64 + lane;    // slot in half-tile [0,1024)
        const int g  = s >> 6;                        // subtile 0..15
        const int r4 = (s >> 2) & 15;
        const int c4 = (s & 3) ^ ((r4 >> 1) & 3);     // un-swizzled chunk
        const int row = ((g >> 1) << 4) + r4;         // 0..127 (half-local)
        const int cb  = (((g & 1) << 2) + c4) << 4;   // byte col 0..112
        pA[q] = (const char*)A  + (size_t)(mTile + row) * Kb + cb;
        pB[q] = (const char*)Bt + (size_t)(nTile + row) * Kb + cb;
    }
    const size_t HSTEP = (size_t)128 * Kb;    // +128 rows (half 1)
    const int w2k = wave * 2048;              // this wave's q0 slice byte base

    // swizzled ds_read lane offset (within a 1024B subtile, +ks*1024 +g_r*2048)
    const int laneoff = ((lane & 15) << 6)
                      + ((((lane >> 4) ^ (((lane & 15) >> 1) & 3))) << 4);

    f32x4 acc[8][4] = {};
    const int NT = K >> 6;

#define STG_A(buf, t, h) do {                                                  \
    char* _d = lds + (buf) * 65536 + (h) * 16384 + w2k;                        \
    lds16(pA[0] + (size_t)(h) * HSTEP + (size_t)(t) * 128, _d);                \
    lds16(pA[1] + (size_t)(h) * HSTEP + (size_t)(t) * 128, _d + 1024);         \
} while (0)
#define STG_B(buf, t, h) do {                                                  \
    char* _d = lds + 32768 + (buf) * 65536 + (h) * 16384 + w2k;                \
    lds16(pB[0] + (size_t)(h) * HSTEP + (size_t)(t) * 128, _d);                \
    lds16(pB[1] + (size_t)(h) * HSTEP + (size_t)(t) * 128, _d + 1024);         \
} while (0)
#define LDA(dst, buf, mi, ks) dst = *(const bf16x8*)(lds + (buf) * 65536       \
        + ((wr * 8 + (mi)) * 2048) + (ks) * 1024 + laneoff)
#define LDB(dst, buf, ni, ks) dst = *(const bf16x8*)(lds + 32768               \
        + (buf) * 65536 + ((wc * 4 + (ni)) * 2048) + (ks) * 1024 + laneoff)
#define BAR() __builtin_amdgcn_s_barrier()
#define LGKM0() asm volatile("s_waitcnt lgkmcnt(0)" ::: "memory")
#define MFMA_Q(p)                                                              \
    __builtin_amdgcn_s_setprio(1);                                             \
    { _Pragma("unroll")                                                        \
      for (int ii = 0; ii < 2; ++ii) {                                         \
        _Pragma("unroll")                                                      \
        for (int ni = 0; ni < 4; ++ni) {                                       \
          _Pragma("unroll")                                                    \
          for (int ks = 0; ks < 2; ++ks)                                       \
            acc[2 * (p) + ii][ni] = __builtin_amdgcn_mfma_f32_16x16x32_bf16(   \
                af[ii][ks], bf[ni][ks], acc[2 * (p) + ii][ni], 0, 0, 0);       \
        } } }                                                                  \
    __builtin_amdgcn_s_setprio(0)

    // ---- prologue: stage A(0), B(0), B(1); tile0 must land, B(1) may fly ----
    STG_A(0, 0, 0); STG_A(0, 0, 1);
    STG_B(0, 0, 0); STG_B(0, 0, 1);
    STG_B(1, 1, 0); STG_B(1, 1, 1);
    asm volatile("s_waitcnt vmcnt(4)" ::: "memory");
    BAR();

    bf16x8 af[2][2], bf[4][2];

    for (int t = 0; t < NT; ++t) {
        const int buf = t & 1;
        const int tA = (t + 1 < NT) ? (t + 1) : 0;          // harmless wrap
        int tB = t + 2; if (tB >= NT) tB -= NT;             // harmless wrap

        // ---- phase 0: B(t) all + A-q0 ----
        LDB(bf[0][0], buf, 0, 0); LDB(bf[0][1], buf, 0, 1);
        LDB(bf[1][0], buf, 1, 0); LDB(bf[1][1], buf, 1, 1);
        LDB(bf[2][0], buf, 2, 0); LDB(bf[2][1], buf, 2, 1);
        LDB(bf[3][0], buf, 3, 0); LDB(bf[3][1], buf, 3, 1);
        LDA(af[0][0], buf, 0, 0); LDA(af[0][1], buf, 0, 1);
        LDA(af[1][0], buf, 1, 0); LDA(af[1][1], buf, 1, 1);
        STG_A(buf ^ 1, tA, 0);
        BAR(); LGKM0();
        MFMA_Q(0);
        BAR();

        // ---- phase 1: A-q1 ----
        LDA(af[0][0], buf, 2, 0); LDA(af[0][1], buf, 2, 1);
        LDA(af[1][0], buf, 3, 0); LDA(af[1][1], buf, 3, 1);
        STG_A(buf ^ 1, tA, 1);
        BAR(); LGKM0();
        MFMA_Q(1);
        BAR();

        // ---- phase 2: A-q2 ----
        LDA(af[0][0], buf, 4, 0); LDA(af[0][1], buf, 4, 1);
        LDA(af[1][0], buf, 5, 0); LDA(af[1][1], buf, 5, 1);
        STG_B(buf, tB, 0);
        BAR(); LGKM0();
        MFMA_Q(2);
        BAR();

        // ---- phase 3: A-q3, counted vmcnt (A(t+1)+B(t+1) landed; B(t+2) in flight) ----
        LDA(af[0][0], buf, 6, 0); LDA(af[0][1], buf, 6, 1);
        LDA(af[1][0], buf, 7, 0); LDA(af[1][1], buf, 7, 1);
        STG_B(buf, tB, 1);
        asm volatile("s_waitcnt vmcnt(4)" ::: "memory");
        BAR(); LGKM0();
        MFMA_Q(3);
        BAR();
    }

    // ---- epilogue: C/D layout col=lane&15, row=(lane>>4)*4+reg ----
    const float nmk = *nmk_p;
    const int l15 = lane & 15, lh = lane >> 4;
    float bn[4];
#pragma unroll
    for (int ni = 0; ni < 4; ++ni) bn[ni] = bias[nTile + wc * 64 + ni * 16 + l15];

#pragma unroll
    for (int mi = 0; mi < 8; ++mi) {
        const int rbase = mTile + wr * 128 + mi * 16 + lh * 4;
#pragma unroll
        for (int ni = 0; ni < 4; ++ni) {
            const int col = nTile + wc * 64 + ni * 16 + l15;
#pragma unroll
            for (int reg = 0; reg < 4; ++reg) {
                C[(size_t)(rbase + reg) * N + col] = nmk * acc[mi][ni][reg] + bn[ni];
            }
        }
    }
#undef STG_A
#undef STG_B
#undef LDA
#undef LDB
#undef BAR
#undef LGKM0
#undef MFMA_Q
}

// ---------------- fallback (odd shapes / tiny ws): fp32 tiled ----------------
__global__ void fallback_gemm(const float* __restrict__ x, const float* __restrict__ W,
                              const float* __restrict__ bias, const float* __restrict__ nmk_p,
                              const float* __restrict__ kk_p, float* __restrict__ C,
                              int M, int N, int K) {
    __shared__ float At[16][17];
    __shared__ float Bq[16][17];
    const int tx = threadIdx.x, ty = threadIdx.y;
    const int n = blockIdx.x * 16 + tx;
    const int m = blockIdx.y * 16 + ty;
    const float kk = *kk_p;
    const bool soft = kk < 1000.f;
    float acc = 0.f;
    for (int k0 = 0; k0 < K; k0 += 16) {
        At[ty][tx] = x[(size_t)m * K + k0 + tx];
        float w = W[(size_t)(k0 + ty) * N + n];
        Bq[ty][tx] = soft ? tanhf(w * kk) : (w > 0.f ? 1.f : (w < 0.f ? -1.f : 0.f));
        __syncthreads();
#pragma unroll
        for (int kk2 = 0; kk2 < 16; ++kk2) acc += At[ty][kk2] * Bq[kk2][tx];
        __syncthreads();
    }
    C[(size_t)m * N + n] = (*nmk_p) * acc + bias[n];
}

extern "C" void kernel_launch(void* const* d_in, const int* in_sizes, int n_in,
                              void* d_out, int out_size, void* d_ws, size_t ws_size,
                              hipStream_t stream) {
    const float* x    = (const float*)d_in[0];
    const float* W    = (const float*)d_in[1];
    const float* bias = (const float*)d_in[2];
    const float* nmk  = (const float*)d_in[3];
    const float* kk   = (const float*)d_in[4];
    float* out = (float*)d_out;

    const int N = in_sizes[2];            // 4096 (bias length)
    const int K = in_sizes[1] / N;        // 4096
    const int M = in_sizes[0] / K;        // 8192

    const size_t need = ((size_t)M * K + (size_t)N * K) * sizeof(unsigned short);
    const bool shapes_ok = (M % 256 == 0) && (N % 256 == 0) && (K % 64 == 0) &&
                           (K >= 128) && ((M * K) % 2048 == 0);

    if (ws_size >= need && shapes_ok) {
        unsigned short* xb = (unsigned short*)d_ws;         // M*K bf16
        unsigned short* Wt = xb + (size_t)M * K;            // N*K bf16 (W^T, quantized)

        const int n8 = (M * K) / 8;
        const int qbx = N / 64;
        const int qblocks = qbx * (K / 64);
        const int cblocks = (n8 + 255) / 256;
        prep<<<qblocks + cblocks, 256, 0, stream>>>(x, xb, n8, W, Wt, kk, K, N, qbx, qblocks);

        const int nwg = (M / 256) * (N / 256);
        gemm_bf16_256<<<nwg, 512, 0, stream>>>(xb, Wt, bias, nmk, out, M, N, K);
    } else {
        dim3 fg(N / 16, M / 16);
        fallback_gemm<<<fg, dim3(16, 16), 0, stream>>>(x, W, bias, nmk, kk, out, M, N, K);
    }
}